// Round 7
// baseline (694.853 us; speedup 1.0000x reference)
//
#include <hip/hip_runtime.h>
#include <hip/hip_bf16.h>
#include <math.h>

// ---------------------------------------------------------------------------
// VQVAE forward.
//  - m97-style 1-phase 128x128 bf16 MFMA GEMM (measured-best core, round 3)
//  - vae_sample fused into mu_logvar GEMM epilogue (W2 row-permuted)
//  - z_e + logits merged into ONE plain-bf16 GEMM (B = [W_enc | cbW] concat);
//    argmax protected by fp64 near-tie repair (gap < 2e-2)
// Outputs: x_tilde[16384,768], z_e_x[16384,500], z_q_x[16384,500],
// logits[16384,43], kl_div[1]
// ---------------------------------------------------------------------------

#define B_ROWS 16384

typedef __attribute__((ext_vector_type(8))) short bf16x8;
typedef __attribute__((ext_vector_type(4))) float f32x4;

constexpr size_t X_TILDE_OFF = 0;
constexpr size_t ZE_OFF      = 12582912;
constexpr size_t ZQ_OFF      = 20774912;
constexpr size_t LOG_OFF     = 28966912;
constexpr size_t KL_OFF      = 29671424;

// ws byte offsets (~103 MB total)
constexpr size_t WS_XH  = 0;            // [16384][768]  bf16 x
constexpr size_t WS_ZB  = 25165824;     // [16384][1088] bf16 concat [z|y]
constexpr size_t WS_HB  = 60817408;     // [16384][1024] bf16 h
constexpr size_t WS_W1B = 94371840;     // [1024][768]  bf16
constexpr size_t WS_W2P = 95944704;     // [2048][1024] bf16, row-permuted
constexpr size_t WS_WDB = 100139008;    // [768][1088]  bf16
constexpr size_t WS_WEC = 101810176;    // [640][768]   bf16: rows 0-499 W_enc,
                                        //   500-511 zero, 512-554 cbW, rest 0
constexpr size_t WS_CBD = 102793216;    // [43][768]    f64 cbW (repair)
constexpr size_t WS_LBF = 103057408;    // [64]         f32 logits bias
constexpr size_t WS_LBD = 103057664;    // [43]         f64 logits bias

__device__ __forceinline__ unsigned short f2b(float f) {
    unsigned u = __builtin_bit_cast(unsigned, f);
    return (unsigned short)((u + 0x7FFFu + ((u >> 16) & 1u)) >> 16);
}
__device__ __forceinline__ float b2f(unsigned short u) {
    return __uint_as_float(((unsigned)u) << 16);
}

__device__ __forceinline__ void stage16(const void* g, void* l) {
    __builtin_amdgcn_global_load_lds(
        (const __attribute__((address_space(1))) void*)g,
        (__attribute__((address_space(3))) void*)l, 16, 0, 0);
}

enum { EPI_H = 0, EPI_XT = 1, EPI_ZL = 2, EPI_ML = 3 };

// ---------------------------------------------------------------------------
// 1-phase 128x128 tile, BK=32, 4 waves, 4x4 16x16x32 frags (round-3 core:
// measured 108us / 636 TF on the ML shape; ~2.5 blocks/CU implicit overlap).
// ---------------------------------------------------------------------------
template<int EPI>
__global__ __launch_bounds__(256) void gemm1(
    const unsigned short* __restrict__ A,
    const unsigned short* __restrict__ Bw,
    const float* __restrict__ bias,    // H: b1 | ML: b2 | ZL: b_enc | XT: bd
    const float* __restrict__ bias2,   // ZL: lbf
    void* __restrict__ Cv,             // H: hb | ML: Zb | ZL: z_e f32 | XT: f32
    float* __restrict__ C2,            // ZL: logits
    const float* __restrict__ eps,     // ML only
    float* __restrict__ kl,            // ML only
    int lda, int ldb, int ldc, int K)
{
    __shared__ short As[128 * 32];
    __shared__ short Bs[128 * 32];
    __shared__ float wsum[4];
    const int t  = threadIdx.x;
    const int w  = t >> 6, l = t & 63;
    const int row0 = blockIdx.y * 128;
    const int col0 = blockIdx.x * 128;
    const int wr = (w >> 1) * 64, wc = (w & 1) * 64;

    const unsigned short* a0 = A  + (size_t)(row0 + (t >> 2)) * lda + ((t & 3) << 3);
    const unsigned short* b0 = Bw + (size_t)(col0 + (t >> 2)) * ldb + ((t & 3) << 3);
    const size_t aStep = (size_t)64 * lda;
    const size_t bStep = (size_t)64 * ldb;
    short* lA0 = As + t * 8;       short* lA1 = As + (256 + t) * 8;
    short* lB0 = Bs + t * 8;       short* lB1 = Bs + (256 + t) * 8;

    f32x4 acc[4][4] = {};
    const int fr = l & 15;
    const int fk = (l >> 4) << 3;

    for (int k0 = 0; k0 < K; k0 += 32) {
        stage16(a0 + k0, lA0);
        stage16(a0 + aStep + k0, lA1);
        stage16(b0 + k0, lB0);
        stage16(b0 + bStep + k0, lB1);
        __syncthreads();
        bf16x8 am[4], bn[4];
        #pragma unroll
        for (int i = 0; i < 4; ++i)
            am[i] = *(const bf16x8*)&As[(wr + i * 16 + fr) * 32 + fk];
        #pragma unroll
        for (int j = 0; j < 4; ++j)
            bn[j] = *(const bf16x8*)&Bs[(wc + j * 16 + fr) * 32 + fk];
        #pragma unroll
        for (int i = 0; i < 4; ++i)
            #pragma unroll
            for (int j = 0; j < 4; ++j)
                acc[i][j] = __builtin_amdgcn_mfma_f32_16x16x32_bf16(
                    am[i], bn[j], acc[i][j], 0, 0, 0);
        __syncthreads();
    }

    // C/D layout: col = lane&15, row = (lane>>4)*4 + reg   [m89/m91]
    const int fq = (l >> 4) << 2;

    if constexpr (EPI == EPI_ML) {
        // frag pair (2jj, 2jj+1) = (mu, logvar) of vae dim d (W2 row-perm)
        float klsum = 0.f;
        const int dbase = (col0 + wc) >> 1;
        #pragma unroll
        for (int i = 0; i < 4; ++i) {
            #pragma unroll
            for (int jj = 0; jj < 2; ++jj) {
                const int d = dbase + jj * 16 + fr;
                const float bmu = bias[d], blv = bias[1024 + d];
                #pragma unroll
                for (int q = 0; q < 4; ++q) {
                    const int r = row0 + wr + i * 16 + fq + q;
                    const float mu = acc[i][2 * jj][q] + bmu;
                    const float lv = acc[i][2 * jj + 1][q] + blv;
                    const float e  = eps[(size_t)r * 1024 + d];
                    const float z  = fmaf(expf(0.5f * lv), e, mu);
                    ((unsigned short*)Cv)[(size_t)r * 1088 + d] = f2b(z);
                    klsum += 0.5f * (expf(lv) + mu * mu - 1.f - lv);
                }
            }
        }
        #pragma unroll
        for (int off = 32; off; off >>= 1) klsum += __shfl_xor(klsum, off);
        if (l == 0) wsum[w] = klsum;
        __syncthreads();
        if (t == 0)
            atomicAdd(kl, (wsum[0] + wsum[1] + wsum[2] + wsum[3]) * (1.0f / 16384.f));
    } else if constexpr (EPI == EPI_ZL) {
        #pragma unroll
        for (int i = 0; i < 4; ++i) {
            #pragma unroll
            for (int j = 0; j < 4; ++j) {
                const int c = col0 + wc + j * 16 + fr;
                const int r0 = row0 + wr + i * 16 + fq;
                if (c < 500) {
                    const float bv = bias[c];
                    #pragma unroll
                    for (int q = 0; q < 4; ++q)
                        ((float*)Cv)[(size_t)(r0 + q) * 500 + c] = acc[i][j][q] + bv;
                } else if (c >= 512 && c < 555) {
                    const float bv = bias2[c - 512];
                    #pragma unroll
                    for (int q = 0; q < 4; ++q)
                        C2[(size_t)(r0 + q) * 43 + (c - 512)] = acc[i][j][q] + bv;
                }
            }
        }
    } else {
        #pragma unroll
        for (int i = 0; i < 4; ++i) {
            #pragma unroll
            for (int j = 0; j < 4; ++j) {
                const int c = col0 + wc + j * 16 + fr;
                const int r0 = row0 + wr + i * 16 + fq;
                const float bv = bias[c];
                #pragma unroll
                for (int q = 0; q < 4; ++q) {
                    float v = acc[i][j][q] + bv;
                    if (EPI == EPI_H) {
                        v = fmaxf(v, 0.f);
                        ((unsigned short*)Cv)[(size_t)(r0 + q) * ldc + c] = f2b(v);
                    } else {
                        ((float*)Cv)[(size_t)(r0 + q) * ldc + c] = v;
                    }
                }
            }
        }
    }
}

// ---------------------------------------------------------------------------
// cbW = codebook @ W_enc [43][768] fp64; bf16 of it into WeCat rows 512+j;
// lb = codebook @ b_enc. Grid = 43 blocks.
// ---------------------------------------------------------------------------
__global__ __launch_bounds__(256) void cbw_kernel(
    const float* __restrict__ W_enc, const float* __restrict__ cb,
    const float* __restrict__ b_enc,
    double* __restrict__ cbWd, unsigned short* __restrict__ WeC,
    float* __restrict__ lbf, double* __restrict__ lbd)
{
    const int j = blockIdx.x;   // 0..42
    const int t = threadIdx.x;
    double acc[3] = {0.0, 0.0, 0.0};
    for (int k = 0; k < 500; ++k) {
        const double c = (double)cb[(size_t)j * 500 + k];
        acc[0] = fma(c, (double)W_enc[(size_t)k * 768 + t],       acc[0]);
        acc[1] = fma(c, (double)W_enc[(size_t)k * 768 + t + 256], acc[1]);
        acc[2] = fma(c, (double)W_enc[(size_t)k * 768 + t + 512], acc[2]);
    }
    #pragma unroll
    for (int q = 0; q < 3; ++q) {
        const int d = t + q * 256;
        const double v = acc[q];
        cbWd[(size_t)j * 768 + d] = v;
        WeC[(size_t)(512 + j) * 768 + d] = f2b((float)v);
    }
    if (t == 0) {
        double s = 0.0;
        for (int k = 0; k < 500; ++k)
            s = fma((double)cb[(size_t)j * 500 + k], (double)b_enc[k], s);
        lbd[j] = s;
        lbf[j] = (float)s;
    }
}

// ---------------------------------------------------------------------------
// Head: argmax with fp64 repair for near-ties (gap < 2e-2, covers bf16
// logit error ~1e-3 with 20x margin), softmax, y (bf16) into Zb cols
// 1024..1087, z_q_x = codebook[argmax].
// ---------------------------------------------------------------------------
__global__ __launch_bounds__(256) void head_kernel(
    const float* __restrict__ logits, const float* __restrict__ codebook,
    const int* __restrict__ known_mask, const int* __restrict__ labels,
    const float* __restrict__ x, const double* __restrict__ cbWd,
    const double* __restrict__ lbd,
    float* __restrict__ zq_out, unsigned short* __restrict__ Zb)
{
    const int wave = threadIdx.x >> 6;
    const int lane = threadIdx.x & 63;
    const int row  = blockIdx.x * 4 + wave;

    const float* lrow = logits + (size_t)row * 43;
    const float v = (lane < 43) ? lrow[lane] : -INFINITY;

    float bvv = v; int bi = lane;
    #pragma unroll
    for (int off = 32; off; off >>= 1) {
        const float ov = __shfl_xor(bvv, off);
        const int   oi = __shfl_xor(bi, off);
        if (ov > bvv || (ov == bvv && oi < bi)) { bvv = ov; bi = oi; }
    }
    float v2 = (lane == bi) ? -INFINITY : v;
    #pragma unroll
    for (int off = 32; off; off >>= 1) v2 = fmaxf(v2, __shfl_xor(v2, off));

    int idx = bi;
    if (bvv - v2 < 2e-2f) {   // near-tie: fp64 recompute (wave-uniform)
        double dv = -1.0e300;
        if (lane < 43) {
            double s = lbd[lane];
            const float* xr = x + (size_t)row * 768;
            const double* wrow = cbWd + (size_t)lane * 768;
            for (int d = 0; d < 768; ++d)
                s = fma((double)xr[d], wrow[d], s);
            dv = s;
        }
        double bdv = dv; int bj = lane;
        #pragma unroll
        for (int off = 32; off; off >>= 1) {
            const double ov = __shfl_xor(bdv, off);
            const int    oi = __shfl_xor(bj, off);
            if (ov > bdv || (ov == bdv && oi < bj)) { bdv = ov; bj = oi; }
        }
        idx = bj;
    }

    float e = (lane < 43) ? expf(v - bvv) : 0.f;
    float s = e;
    #pragma unroll
    for (int off = 32; off; off >>= 1) s += __shfl_xor(s, off);

    const int km  = known_mask[row];
    const int lab = labels[row];
    float y;
    if (lane < 43) y = km ? ((lane == lab) ? 1.f : 0.f) : (e / s);
    else           y = 0.f;   // zeros K-pad cols 1067..1087
    Zb[(size_t)row * 1088 + 1024 + lane] = f2b(y);

    const float* crow = codebook + (size_t)idx * 500;
    float* zrow = zq_out + (size_t)row * 500;
    for (int c = lane; c < 500; c += 64) zrow[c] = crow[c];
}

// f32 -> bf16 (RNE), n % 4 == 0
__global__ __launch_bounds__(256) void conv_bf16(
    const float* __restrict__ in, unsigned short* __restrict__ out, int n)
{
    const int i = (blockIdx.x * 256 + threadIdx.x) * 4;
    if (i >= n) return;
    const float4 v = *(const float4*)(in + i);
    ushort4 o;
    o.x = f2b(v.x); o.y = f2b(v.y); o.z = f2b(v.z); o.w = f2b(v.w);
    *(ushort4*)(out + i) = o;
}

// WeCat fill: rows 0-499 = bf16(W_enc), rows 500-639 = 0 (512-554 later
// overwritten by cbw_kernel).
__global__ __launch_bounds__(256) void wecat_fill(
    const float* __restrict__ W, unsigned short* __restrict__ WeC)
{
    const int idx = blockIdx.x * 256 + threadIdx.x;
    if (idx >= 640 * 768) return;
    const int r = idx / 768;
    WeC[idx] = (r < 500) ? f2b(W[idx]) : 0;
}

// W2 [2048][1024] -> W2p [2048][1024] bf16, rows permuted so that output
// col 32g+s (s<16) = mu_{16g+s} and col 32g+16+s = logvar_{16g+s}.
__global__ __launch_bounds__(256) void repack_w2p(
    const float* __restrict__ W2, unsigned short* __restrict__ W2p)
{
    const int idx = blockIdx.x * 256 + threadIdx.x;
    if (idx >= 2048 * 1024) return;
    const int c = idx >> 10;
    const int k = idx & 1023;
    const int s = c & 31, g = c >> 5;
    const int src = ((s < 16) ? 0 : 1024) + g * 16 + (s & 15);
    W2p[idx] = f2b(W2[(size_t)src * 1024 + k]);
}

// Wd [768][1067] f32 -> [768][1088] bf16, zero K-pad
__global__ __launch_bounds__(256) void repack_wd(
    const float* __restrict__ Wd, unsigned short* __restrict__ Wdb)
{
    const int idx = blockIdx.x * 256 + threadIdx.x;
    if (idx >= 768 * 1088) return;
    const int n = idx / 1088;
    const int k = idx - n * 1088;
    Wdb[idx] = (k < 1067) ? f2b(Wd[(size_t)n * 1067 + k]) : 0;
}

extern "C" void kernel_launch(void* const* d_in, const int* in_sizes, int n_in,
                              void* d_out, int out_size, void* d_ws, size_t ws_size,
                              hipStream_t stream) {
    const float* x        = (const float*)d_in[0];
    const int*   known    = (const int*)  d_in[1];
    const int*   labels   = (const int*)  d_in[2];
    const float* eps      = (const float*)d_in[3];
    const float* W_enc    = (const float*)d_in[4];
    const float* b_enc    = (const float*)d_in[5];
    const float* codebook = (const float*)d_in[6];
    const float* W1       = (const float*)d_in[7];
    const float* b1       = (const float*)d_in[8];
    const float* W2       = (const float*)d_in[9];
    const float* b2       = (const float*)d_in[10];
    const float* Wd       = (const float*)d_in[11];
    const float* bd       = (const float*)d_in[12];
    float* out = (float*)d_out;
    char*  ws  = (char*)d_ws;

    unsigned short* xh   = (unsigned short*)(ws + WS_XH);
    unsigned short* Zb   = (unsigned short*)(ws + WS_ZB);
    unsigned short* hb   = (unsigned short*)(ws + WS_HB);
    unsigned short* W1b  = (unsigned short*)(ws + WS_W1B);
    unsigned short* W2p  = (unsigned short*)(ws + WS_W2P);
    unsigned short* Wdb  = (unsigned short*)(ws + WS_WDB);
    unsigned short* WeC  = (unsigned short*)(ws + WS_WEC);
    double*         cbWd = (double*)        (ws + WS_CBD);
    float*          lbf  = (float*)         (ws + WS_LBF);
    double*         lbd  = (double*)        (ws + WS_LBD);

    hipMemsetAsync(out + KL_OFF, 0, sizeof(float), stream);

    const dim3 blk(256);
    conv_bf16<<<(16384 * 768 / 4 + 255) / 256, blk, 0, stream>>>(x, xh, 16384 * 768);
    conv_bf16<<<(1024 * 768 / 4 + 255) / 256, blk, 0, stream>>>(W1, W1b, 1024 * 768);
    repack_w2p<<<(2048 * 1024 + 255) / 256, blk, 0, stream>>>(W2, W2p);
    repack_wd<<<(768 * 1088 + 255) / 256, blk, 0, stream>>>(Wd, Wdb);
    wecat_fill<<<(640 * 768 + 255) / 256, blk, 0, stream>>>(W_enc, WeC);
    cbw_kernel<<<43, blk, 0, stream>>>(W_enc, codebook, b_enc, cbWd, WeC, lbf, lbd);

    // h = relu(x @ W1^T + b1)   [16384,1024] bf16
    gemm1<EPI_H><<<dim3(8, 128), blk, 0, stream>>>(
        xh, W1b, b1, nullptr, hb, nullptr, nullptr, nullptr, 768, 768, 1024, 768);
    // mu_logvar GEMM fused with sampling + KL -> Zb cols 0..1023
    gemm1<EPI_ML><<<dim3(16, 128), blk, 0, stream>>>(
        hb, W2p, b2, nullptr, Zb, nullptr, eps, out + KL_OFF, 1024, 1024, 0, 1024);
    // z_e (cols<500) + logits (cols 512..554) in one GEMM, N=640
    gemm1<EPI_ZL><<<dim3(5, 128), blk, 0, stream>>>(
        xh, WeC, b_enc, lbf, out + ZE_OFF, out + LOG_OFF, nullptr, nullptr,
        768, 768, 500, 768);
    // head: argmax(+fp64 repair)/softmax/y/z_q_x
    head_kernel<<<B_ROWS / 4, blk, 0, stream>>>(
        out + LOG_OFF, codebook, known, labels, x, cbWd, lbd,
        out + ZQ_OFF, Zb);
    // x_tilde = [sampled_z | y] @ Wd^T + bd   [16384,768] f32
    gemm1<EPI_XT><<<dim3(6, 128), blk, 0, stream>>>(
        Zb, Wdb, bd, nullptr, out + X_TILDE_OFF, nullptr, nullptr, nullptr,
        1088, 1088, 768, 1088);
}